// Round 8
// baseline (304.217 us; speedup 1.0000x reference)
//
#include <hip/hip_runtime.h>

#define KN 32      // neighbors
#define NF 128     // feature dim
#define NH 4       // heads
#define HD 256     // H*D
#define NC 40      // classes
#define NPB 8      // nodes per block
#define XS2 132    // Xs row stride (bf16 elems): banks balanced for uniform-row reads

// ws layout (floats): [0,512)=w_src[h][f], [512,1024)=w_dst[h][f],
//   [1024,21504)=MT[cls][h*128+f], [21504, 21504+4*n)=ei[n][h]
#define WS_WSRC 0
#define WS_WDST 512
#define WS_MT   1024
#define WS_EI   (1024 + NC * 512)

static __device__ __forceinline__ unsigned short bf16_of(float x) {
    union { float f; unsigned u; } v; v.f = x;
    unsigned r = v.u + 0x7FFFu + ((v.u >> 16) & 1u);   // round-to-nearest-even
    return (unsigned short)(r >> 16);
}
static __device__ __forceinline__ float f_of_bf16(unsigned short b) {
    union { unsigned u; float f; } v; v.u = ((unsigned)b) << 16; return v.f;
}

// w_src[h][f] = sum_d W[f][h*64+d] * a_src[h][d]  (same for dst)
__global__ void gat_prep_ws(const float* __restrict__ W,
                            const float* __restrict__ a_src,
                            const float* __restrict__ a_dst,
                            float* __restrict__ ws)
{
    int g = blockIdx.x * blockDim.x + threadIdx.x;
    if (g >= 1024) return;
    int which = g >> 9, h = (g >> 7) & 3, f = g & 127;
    const float* a = which ? a_dst : a_src;
    float s = 0.f;
    #pragma unroll 8
    for (int d = 0; d < 64; ++d)
        s = fmaf(W[f * HD + h * 64 + d], a[h * 64 + d], s);
    ws[g] = s;
}

// MT[cls][h*128+f] = sum_d W[f][h*64+d] * cls_w[h*64+d][cls]
__global__ void gat_prep_mt(const float* __restrict__ W,
                            const float* __restrict__ cls_w,
                            float* __restrict__ ws)
{
    int g = blockIdx.x * blockDim.x + threadIdx.x;
    if (g >= NC * 512) return;
    int cls = g >> 9, c = g & 511;
    int h = c >> 7, f = c & 127;
    float s = 0.f;
    #pragma unroll 8
    for (int d = 0; d < 64; ++d)
        s = fmaf(W[f * HD + h * 64 + d], cls_w[(h * 64 + d) * NC + cls], s);
    ws[WS_MT + (size_t)cls * 512 + c] = s;
}

// ei[n][h] = sum_f nodef[n][f] * w_src[h][f]   (4 lanes per node, quad shuffle)
__global__ void gat_prep_ei(const float* __restrict__ nodef,
                            float* __restrict__ ws, int n_nodes)
{
    const int t = threadIdx.x;
    const int lane = t & 63;
    const int node = blockIdx.x * 64 + (t >> 6) * 16 + (lane >> 2);
    const int q = lane & 3;
    if (node >= n_nodes) return;   // whole quad exits together
    const float* wsrc = ws + WS_WSRC;
    const float4* xp = (const float4*)(nodef + (size_t)node * NF + q * 32);
    float p0 = 0.f, p1 = 0.f, p2 = 0.f, p3 = 0.f;
    #pragma unroll
    for (int j = 0; j < 8; ++j) {
        float4 x  = xp[j];
        float4 w0 = *(const float4*)&wsrc[0 * NF + q * 32 + 4 * j];
        float4 w1 = *(const float4*)&wsrc[1 * NF + q * 32 + 4 * j];
        float4 w2 = *(const float4*)&wsrc[2 * NF + q * 32 + 4 * j];
        float4 w3 = *(const float4*)&wsrc[3 * NF + q * 32 + 4 * j];
        p0 += x.x*w0.x + x.y*w0.y + x.z*w0.z + x.w*w0.w;
        p1 += x.x*w1.x + x.y*w1.y + x.z*w1.z + x.w*w1.w;
        p2 += x.x*w2.x + x.y*w2.y + x.z*w2.z + x.w*w2.w;
        p3 += x.x*w3.x + x.y*w3.y + x.z*w3.z + x.w*w3.w;
    }
    #pragma unroll
    for (int st = 1; st < 4; st <<= 1) {
        p0 += __shfl_xor(p0, st); p1 += __shfl_xor(p1, st);
        p2 += __shfl_xor(p2, st); p3 += __shfl_xor(p3, st);
    }
    if (q == 0)
        *(float4*)&ws[WS_EI + (size_t)node * 4] = make_float4(p0, p1, p2, p3);
}

// One node: stage tile (bf16), e_j dots from fp32 regs, ONE barrier, fused
// exp-softmax + aggregation (no max-subtract: |e|max ~ 10 << fp32 exp range).
__device__ __forceinline__ void gat_body(
    int i_, unsigned short* __restrict__ XsB, float* __restrict__ eB,
    unsigned short* __restrict__ zrow, float4 xv[4], const float4 wd[4][4],
    const float* __restrict__ neigh, const float* __restrict__ ei_g,
    int node0, int kq, int fq, int wv, int f2)
{
    // stage tile into this parity's LDS buffer as bf16 (e_j uses fp32 regs)
    #pragma unroll
    for (int j = 0; j < 4; ++j) {
        ushort4 pk;
        pk.x = bf16_of(xv[j].x); pk.y = bf16_of(xv[j].y);
        pk.z = bf16_of(xv[j].z); pk.w = bf16_of(xv[j].w);
        *(ushort4*)&XsB[kq * XS2 + fq * 4 + 32 * j] = pk;
    }

    // wave-uniform e_i (head == wave id), L2-hot
    const float ei_h = ei_g[(size_t)(node0 + i_) * 4 + wv];

    // e_j partial dots from fp32 registers
    float s0 = 0.f, s1 = 0.f, s2 = 0.f, s3 = 0.f;
    #pragma unroll
    for (int j = 0; j < 4; ++j) {
        float4 x = xv[j];
        s0 += x.x*wd[0][j].x + x.y*wd[0][j].y + x.z*wd[0][j].z + x.w*wd[0][j].w;
        s1 += x.x*wd[1][j].x + x.y*wd[1][j].y + x.z*wd[1][j].z + x.w*wd[1][j].w;
        s2 += x.x*wd[2][j].x + x.y*wd[2][j].y + x.z*wd[2][j].z + x.w*wd[2][j].w;
        s3 += x.x*wd[3][j].x + x.y*wd[3][j].y + x.z*wd[3][j].z + x.w*wd[3][j].w;
    }

    // depth-2 prefetch: xv dead, reload with node i_+2
    if (i_ + 2 < NPB) {
        const float4* src = (const float4*)(neigh + ((size_t)(node0 + i_ + 2) * KN + kq) * NF);
        #pragma unroll
        for (int j = 0; j < 4; ++j) xv[j] = src[fq + 8 * j];
    }

    // reduce e_j over the 8 feature-slices
    #pragma unroll
    for (int st = 1; st < 8; st <<= 1) {
        s0 += __shfl_xor(s0, st); s1 += __shfl_xor(s1, st);
        s2 += __shfl_xor(s2, st); s3 += __shfl_xor(s3, st);
    }
    if (fq == 0) {                       // 32 writers -> 32 distinct banks
        eB[0 * KN + kq] = s0; eB[1 * KN + kq] = s1;
        eB[2 * KN + kq] = s2; eB[3 * KN + kq] = s3;
    }
    __syncthreads();   // B1: e + tile ready (the ONLY barrier per node)

    // fused softmax + aggregation; thread owns (head=wv, cols f2,f2+1)
    float ss = 0.f, zx = 0.f, zy = 0.f;
    #pragma unroll
    for (int m = 0; m < 8; ++m) {
        float4 evm = *(const float4*)&eB[wv * KN + m * 4];   // broadcast
        float el[4] = {evm.x, evm.y, evm.z, evm.w};
        #pragma unroll
        for (int kk = 0; kk < 4; ++kk) {
            float z_ = ei_h + el[kk];
            float l_ = fmaxf(z_, 0.2f * z_);       // LeakyReLU
            float p_ = __expf(l_);
            ss += p_;
            ushort2 xb = *(const ushort2*)&XsB[(m * 4 + kk) * XS2 + f2];
            zx = fmaf(p_, f_of_bf16(xb.x), zx);
            zy = fmaf(p_, f_of_bf16(xb.y), zy);
        }
    }
    float inv = 1.f / ss;
    ushort2 zo; zo.x = bf16_of(zx * inv); zo.y = bf16_of(zy * inv);
    *(ushort2*)&zrow[wv * NF + f2] = zo;
}

__global__ __launch_bounds__(256, 6)
void gat_main(const float* __restrict__ neigh,
              const float* __restrict__ ws,
              float* __restrict__ out, int n_nodes)
{
    __shared__ __align__(16) unsigned short Xs[2][KN * XS2];  // 16.9 KB dbuf tile (bf16)
    __shared__ __align__(16) unsigned short zlB[NPB][512];    // 8 KB aggregated feats (bf16)
    __shared__ __align__(16) float e_lds[2][NH * KN];         // 1 KB dbuf logits

    const int t  = threadIdx.x;
    const int kq = t >> 3;          // neighbor row 0..31
    const int fq = t & 7;           // feature-slice id
    const int wv = t >> 6;          // wave id == head in agg phase
    const int f2 = (t & 63) * 2;    // feature pair in agg phase
    const float* wdst = ws + WS_WDST;
    const float* MT   = ws + WS_MT;
    const float* ei_g = ws + WS_EI;

    const int node0 = blockIdx.x * NPB;
    if (node0 >= n_nodes) return;

    // register-cached w~dst slices
    float4 wd[4][4];
    #pragma unroll
    for (int h = 0; h < 4; ++h)
        #pragma unroll
        for (int j = 0; j < 4; ++j)
            wd[h][j] = *(const float4*)&wdst[h * NF + fq * 4 + 32 * j];

    // prologue: depth-2 prefetch (nodes node0, node0+1)
    float4 xvA[4], xvB[4];
    {
        const float4* sA = (const float4*)(neigh + ((size_t)node0 * KN + kq) * NF);
        const float4* sB = (const float4*)(neigh + ((size_t)(node0 + 1) * KN + kq) * NF);
        #pragma unroll
        for (int j = 0; j < 4; ++j) { xvA[j] = sA[fq + 8 * j]; xvB[j] = sB[fq + 8 * j]; }
    }

    #pragma unroll
    for (int ii = 0; ii < NPB; ii += 2) {
        gat_body(ii,     Xs[0], e_lds[0], zlB[ii],     xvA, wd, neigh, ei_g,
                 node0, kq, fq, wv, f2);
        gat_body(ii + 1, Xs[1], e_lds[1], zlB[ii + 1], xvB, wd, neigh, ei_g,
                 node0, kq, fq, wv, f2);
    }
    __syncthreads();

    // ---- fused classifier: y[i][cls] = zl[i][:] . MT[cls][:] ----
    float* ypart = (float*)&Xs[0][0];   // Xs dead; ypart[s][i][cls]
    {
        int cls = t & 63, s = t >> 6;
        if (cls < NC) {
            const float4* mp = (const float4*)&MT[(size_t)cls * 512 + s * 128];
            float acc[NPB];
            #pragma unroll
            for (int i = 0; i < NPB; ++i) acc[i] = 0.f;
            #pragma unroll 2
            for (int c4 = 0; c4 < 32; ++c4) {
                float4 mv = mp[c4];
                #pragma unroll
                for (int i = 0; i < NPB; ++i) {
                    ushort4 zv = *(const ushort4*)&zlB[i][s * 128 + c4 * 4];  // broadcast
                    acc[i] += f_of_bf16(zv.x) * mv.x + f_of_bf16(zv.y) * mv.y
                            + f_of_bf16(zv.z) * mv.z + f_of_bf16(zv.w) * mv.w;
                }
            }
            #pragma unroll
            for (int i = 0; i < NPB; ++i)
                ypart[s * (NPB * NC) + i * NC + cls] = acc[i];
        }
    }
    __syncthreads();
    #pragma unroll
    for (int rep = 0; rep < 2; ++rep) {
        int p = t + rep * 256;
        if (p < NPB * NC) {
            float y = ypart[p] + ypart[NPB * NC + p]
                    + ypart[2 * NPB * NC + p] + ypart[3 * NPB * NC + p];
            out[(size_t)node0 * NC + p] = y;   // consecutive -> coalesced
        }
    }
}

extern "C" void kernel_launch(void* const* d_in, const int* in_sizes, int n_in,
                              void* d_out, int out_size, void* d_ws, size_t ws_size,
                              hipStream_t stream) {
    const float* nodef = (const float*)d_in[0];
    const float* neigh = (const float*)d_in[1];
    const float* W     = (const float*)d_in[2];
    const float* a_src = (const float*)d_in[3];
    const float* a_dst = (const float*)d_in[4];
    const float* cls_w = (const float*)d_in[5];
    float* out = (float*)d_out;
    float* ws  = (float*)d_ws;

    const int n_nodes = in_sizes[0] / NF;   // 20000

    hipLaunchKernelGGL(gat_prep_ws, dim3(4), dim3(256), 0, stream, W, a_src, a_dst, ws);
    hipLaunchKernelGGL(gat_prep_ei, dim3((n_nodes + 63) / 64), dim3(256), 0, stream,
                       nodef, ws, n_nodes);
    hipLaunchKernelGGL(gat_prep_mt, dim3((NC * 512 + 255) / 256), dim3(256), 0, stream,
                       W, cls_w, ws);
    hipLaunchKernelGGL(gat_main, dim3((n_nodes + NPB - 1) / NPB), dim3(256), 0, stream,
                       neigh, ws, out, n_nodes);
}

// Round 9
// 161.239 us; speedup vs baseline: 1.8868x; 1.8868x over previous
//
#include <hip/hip_runtime.h>

#define KN 32      // neighbors
#define NF 128     // feature dim
#define NH 4       // heads
#define HD 256     // H*D
#define NC 40      // classes
#define NPB 8      // nodes per block
#define XS2 132    // Xs row stride (bf16 elems)

// ws layout (floats): [0,512)=w_src[h][f], [512,1024)=w_dst[h][f],
//   [1024,21504)=MT[cls][h*128+f], [21504, 21504+4*n)=ei[n][h]
#define WS_WSRC 0
#define WS_WDST 512
#define WS_MT   1024
#define WS_EI   (1024 + NC * 512)

static __device__ __forceinline__ unsigned short bf16_of(float x) {
    union { float f; unsigned u; } v; v.f = x;
    unsigned r = v.u + 0x7FFFu + ((v.u >> 16) & 1u);   // round-to-nearest-even
    return (unsigned short)(r >> 16);
}
static __device__ __forceinline__ float f_of_bf16(unsigned short b) {
    union { unsigned u; float f; } v; v.u = ((unsigned)b) << 16; return v.f;
}

// w_src[h][f] = sum_d W[f][h*64+d] * a_src[h][d]  (same for dst)
__global__ void gat_prep_ws(const float* __restrict__ W,
                            const float* __restrict__ a_src,
                            const float* __restrict__ a_dst,
                            float* __restrict__ ws)
{
    int g = blockIdx.x * blockDim.x + threadIdx.x;
    if (g >= 1024) return;
    int which = g >> 9, h = (g >> 7) & 3, f = g & 127;
    const float* a = which ? a_dst : a_src;
    float s = 0.f;
    #pragma unroll 8
    for (int d = 0; d < 64; ++d)
        s = fmaf(W[f * HD + h * 64 + d], a[h * 64 + d], s);
    ws[g] = s;
}

// MT[cls][h*128+f] = sum_d W[f][h*64+d] * cls_w[h*64+d][cls]
__global__ void gat_prep_mt(const float* __restrict__ W,
                            const float* __restrict__ cls_w,
                            float* __restrict__ ws)
{
    int g = blockIdx.x * blockDim.x + threadIdx.x;
    if (g >= NC * 512) return;
    int cls = g >> 9, c = g & 511;
    int h = c >> 7, f = c & 127;
    float s = 0.f;
    #pragma unroll 8
    for (int d = 0; d < 64; ++d)
        s = fmaf(W[f * HD + h * 64 + d], cls_w[(h * 64 + d) * NC + cls], s);
    ws[WS_MT + (size_t)cls * 512 + c] = s;
}

// ei[n][h] = sum_f nodef[n][f] * w_src[h][f]   (4 lanes per node, quad shuffle)
__global__ void gat_prep_ei(const float* __restrict__ nodef,
                            float* __restrict__ ws, int n_nodes)
{
    const int t = threadIdx.x;
    const int lane = t & 63;
    const int node = blockIdx.x * 64 + (t >> 6) * 16 + (lane >> 2);
    const int q = lane & 3;
    if (node >= n_nodes) return;   // whole quad exits together
    const float* wsrc = ws + WS_WSRC;
    const float4* xp = (const float4*)(nodef + (size_t)node * NF + q * 32);
    float p0 = 0.f, p1 = 0.f, p2 = 0.f, p3 = 0.f;
    #pragma unroll
    for (int j = 0; j < 8; ++j) {
        float4 x  = xp[j];
        float4 w0 = *(const float4*)&wsrc[0 * NF + q * 32 + 4 * j];
        float4 w1 = *(const float4*)&wsrc[1 * NF + q * 32 + 4 * j];
        float4 w2 = *(const float4*)&wsrc[2 * NF + q * 32 + 4 * j];
        float4 w3 = *(const float4*)&wsrc[3 * NF + q * 32 + 4 * j];
        p0 += x.x*w0.x + x.y*w0.y + x.z*w0.z + x.w*w0.w;
        p1 += x.x*w1.x + x.y*w1.y + x.z*w1.z + x.w*w1.w;
        p2 += x.x*w2.x + x.y*w2.y + x.z*w2.z + x.w*w2.w;
        p3 += x.x*w3.x + x.y*w3.y + x.z*w3.z + x.w*w3.w;
    }
    #pragma unroll
    for (int st = 1; st < 4; st <<= 1) {
        p0 += __shfl_xor(p0, st); p1 += __shfl_xor(p1, st);
        p2 += __shfl_xor(p2, st); p3 += __shfl_xor(p3, st);
    }
    if (q == 0)
        *(float4*)&ws[WS_EI + (size_t)node * 4] = make_float4(p0, p1, p2, p3);
}

// One node: stage tile (bf16), e_j dots from fp32 regs, ONE barrier, fused
// exp-softmax + aggregation (no max-subtract: |e|max ~ 10 << fp32 exp range).
__device__ __forceinline__ void gat_body(
    int i_, unsigned short* __restrict__ XsB, float* __restrict__ eB,
    unsigned short* __restrict__ zrow, float4 xv[4], const float4 wd[4][4],
    const float* __restrict__ neigh, const float* __restrict__ ei_g,
    int node0, int kq, int fq, int wv, int f2)
{
    // stage tile into this parity's LDS buffer as bf16 (e_j uses fp32 regs)
    #pragma unroll
    for (int j = 0; j < 4; ++j) {
        ushort4 pk;
        pk.x = bf16_of(xv[j].x); pk.y = bf16_of(xv[j].y);
        pk.z = bf16_of(xv[j].z); pk.w = bf16_of(xv[j].w);
        *(ushort4*)&XsB[kq * XS2 + fq * 4 + 32 * j] = pk;
    }

    // wave-uniform e_i (head == wave id), L2-hot
    const float ei_h = ei_g[(size_t)(node0 + i_) * 4 + wv];

    // e_j partial dots from fp32 registers
    float s0 = 0.f, s1 = 0.f, s2 = 0.f, s3 = 0.f;
    #pragma unroll
    for (int j = 0; j < 4; ++j) {
        float4 x = xv[j];
        s0 += x.x*wd[0][j].x + x.y*wd[0][j].y + x.z*wd[0][j].z + x.w*wd[0][j].w;
        s1 += x.x*wd[1][j].x + x.y*wd[1][j].y + x.z*wd[1][j].z + x.w*wd[1][j].w;
        s2 += x.x*wd[2][j].x + x.y*wd[2][j].y + x.z*wd[2][j].z + x.w*wd[2][j].w;
        s3 += x.x*wd[3][j].x + x.y*wd[3][j].y + x.z*wd[3][j].z + x.w*wd[3][j].w;
    }

    // depth-2 prefetch: xv dead, reload with node i_+2
    if (i_ + 2 < NPB) {
        const float4* src = (const float4*)(neigh + ((size_t)(node0 + i_ + 2) * KN + kq) * NF);
        #pragma unroll
        for (int j = 0; j < 4; ++j) xv[j] = src[fq + 8 * j];
    }

    // reduce e_j over the 8 feature-slices
    #pragma unroll
    for (int st = 1; st < 8; st <<= 1) {
        s0 += __shfl_xor(s0, st); s1 += __shfl_xor(s1, st);
        s2 += __shfl_xor(s2, st); s3 += __shfl_xor(s3, st);
    }
    if (fq == 0) {                       // 32 writers -> 32 distinct banks
        eB[0 * KN + kq] = s0; eB[1 * KN + kq] = s1;
        eB[2 * KN + kq] = s2; eB[3 * KN + kq] = s3;
    }
    __syncthreads();   // B1: e + tile ready (the ONLY barrier per node)

    // fused softmax + aggregation; thread owns (head=wv, cols f2,f2+1)
    float ss = 0.f, zx = 0.f, zy = 0.f;
    #pragma unroll
    for (int m = 0; m < 8; ++m) {
        float4 evm = *(const float4*)&eB[wv * KN + m * 4];   // broadcast
        float el[4] = {evm.x, evm.y, evm.z, evm.w};
        #pragma unroll
        for (int kk = 0; kk < 4; ++kk) {
            float z_ = ei_h + el[kk];
            float l_ = fmaxf(z_, 0.2f * z_);       // LeakyReLU
            float p_ = __expf(l_);
            ss += p_;
            ushort2 xb = *(const ushort2*)&XsB[(m * 4 + kk) * XS2 + f2];
            zx = fmaf(p_, f_of_bf16(xb.x), zx);
            zy = fmaf(p_, f_of_bf16(xb.y), zy);
        }
    }
    float inv = 1.f / ss;
    ushort2 zo; zo.x = bf16_of(zx * inv); zo.y = bf16_of(zy * inv);
    *(ushort2*)&zrow[wv * NF + f2] = zo;
}

__global__ __launch_bounds__(256, 4)
void gat_main(const float* __restrict__ neigh,
              const float* __restrict__ ws,
              float* __restrict__ out, int n_nodes)
{
    __shared__ __align__(16) unsigned short Xs[2][KN * XS2];  // 16.9 KB dbuf tile (bf16)
    __shared__ __align__(16) unsigned short zlB[NPB][512];    // 8 KB aggregated feats (bf16)
    __shared__ __align__(16) float e_lds[2][NH * KN];         // 1 KB dbuf logits

    const int t  = threadIdx.x;
    const int kq = t >> 3;          // neighbor row 0..31
    const int fq = t & 7;           // feature-slice id
    const int wv = t >> 6;          // wave id == head in agg phase
    const int f2 = (t & 63) * 2;    // feature pair in agg phase
    const float* wdst = ws + WS_WDST;
    const float* MT   = ws + WS_MT;
    const float* ei_g = ws + WS_EI;

    const int node0 = blockIdx.x * NPB;
    if (node0 >= n_nodes) return;

    // w~dst slices (compiler may rematerialize from L1 — that's fine)
    float4 wd[4][4];
    #pragma unroll
    for (int h = 0; h < 4; ++h)
        #pragma unroll
        for (int j = 0; j < 4; ++j)
            wd[h][j] = *(const float4*)&wdst[h * NF + fq * 4 + 32 * j];

    // prologue: depth-2 prefetch (nodes node0, node0+1)
    float4 xvA[4], xvB[4];
    {
        const float4* sA = (const float4*)(neigh + ((size_t)node0 * KN + kq) * NF);
        const float4* sB = (const float4*)(neigh + ((size_t)(node0 + 1) * KN + kq) * NF);
        #pragma unroll
        for (int j = 0; j < 4; ++j) { xvA[j] = sA[fq + 8 * j]; xvB[j] = sB[fq + 8 * j]; }
    }

    #pragma unroll
    for (int ii = 0; ii < NPB; ii += 2) {
        gat_body(ii,     Xs[0], e_lds[0], zlB[ii],     xvA, wd, neigh, ei_g,
                 node0, kq, fq, wv, f2);
        gat_body(ii + 1, Xs[1], e_lds[1], zlB[ii + 1], xvB, wd, neigh, ei_g,
                 node0, kq, fq, wv, f2);
    }
    __syncthreads();

    // ---- fused classifier: y[i][cls] = zl[i][:] . MT[cls][:] ----
    float* ypart = (float*)&Xs[0][0];   // Xs dead; ypart[s][i][cls]
    {
        int cls = t & 63, s = t >> 6;
        if (cls < NC) {
            const float4* mp = (const float4*)&MT[(size_t)cls * 512 + s * 128];
            float acc[NPB];
            #pragma unroll
            for (int i = 0; i < NPB; ++i) acc[i] = 0.f;
            #pragma unroll 2
            for (int c4 = 0; c4 < 32; ++c4) {
                float4 mv = mp[c4];
                #pragma unroll
                for (int i = 0; i < NPB; ++i) {
                    ushort4 zv = *(const ushort4*)&zlB[i][s * 128 + c4 * 4];  // broadcast
                    acc[i] += f_of_bf16(zv.x) * mv.x + f_of_bf16(zv.y) * mv.y
                            + f_of_bf16(zv.z) * mv.z + f_of_bf16(zv.w) * mv.w;
                }
            }
            #pragma unroll
            for (int i = 0; i < NPB; ++i)
                ypart[s * (NPB * NC) + i * NC + cls] = acc[i];
        }
    }
    __syncthreads();
    #pragma unroll
    for (int rep = 0; rep < 2; ++rep) {
        int p = t + rep * 256;
        if (p < NPB * NC) {
            float y = ypart[p] + ypart[NPB * NC + p]
                    + ypart[2 * NPB * NC + p] + ypart[3 * NPB * NC + p];
            out[(size_t)node0 * NC + p] = y;   // consecutive -> coalesced
        }
    }
}

extern "C" void kernel_launch(void* const* d_in, const int* in_sizes, int n_in,
                              void* d_out, int out_size, void* d_ws, size_t ws_size,
                              hipStream_t stream) {
    const float* nodef = (const float*)d_in[0];
    const float* neigh = (const float*)d_in[1];
    const float* W     = (const float*)d_in[2];
    const float* a_src = (const float*)d_in[3];
    const float* a_dst = (const float*)d_in[4];
    const float* cls_w = (const float*)d_in[5];
    float* out = (float*)d_out;
    float* ws  = (float*)d_ws;

    const int n_nodes = in_sizes[0] / NF;   // 20000

    hipLaunchKernelGGL(gat_prep_ws, dim3(4), dim3(256), 0, stream, W, a_src, a_dst, ws);
    hipLaunchKernelGGL(gat_prep_ei, dim3((n_nodes + 63) / 64), dim3(256), 0, stream,
                       nodef, ws, n_nodes);
    hipLaunchKernelGGL(gat_prep_mt, dim3((NC * 512 + 255) / 256), dim3(256), 0, stream,
                       W, cls_w, ws);
    hipLaunchKernelGGL(gat_main, dim3((n_nodes + NPB - 1) / NPB), dim3(256), 0, stream,
                       neigh, ws, out, n_nodes);
}